// Round 1
// baseline (117.539 us; speedup 1.0000x reference)
//
#include <hip/hip_runtime.h>
#include <math.h>

#define BATCH 2
#define RAYS  4096
#define NS    48
#define FEAT  32
#define HP    256
#define HID   64
#define NRAY  (BATCH*RAYS)

// steps = n/(N-1), s_delta = 1/(N-1)
#define S_DELTA (1.0f/47.0f)

__device__ __forceinline__ float softplus_f(float t) {
    // log1p(exp(t)) stabilized: max(t,0) + log(1 + exp(-|t|))
    float e = __expf(-fabsf(t));
    return fmaxf(t, 0.0f) + __logf(1.0f + e);
}
__device__ __forceinline__ float sigmoid_f(float t) {
    return 1.0f / (1.0f + __expf(-t));
}

// ---- gather helpers ----------------------------------------------------
// transposed layout: pT[bp][y][x][f], 32 floats contiguous per texel
__device__ __forceinline__ void corner_t(const float* __restrict__ base,
                                         int x, int y, float w, float4 acc[8]) {
    if ((unsigned)x < HP && (unsigned)y < HP) {
        const float4* p = (const float4*)(base + ((size_t)(y * HP + x) * FEAT));
        #pragma unroll
        for (int k = 0; k < 8; ++k) {
            float4 v = p[k];
            acc[k].x = fmaf(w, v.x, acc[k].x);
            acc[k].y = fmaf(w, v.y, acc[k].y);
            acc[k].z = fmaf(w, v.z, acc[k].z);
            acc[k].w = fmaf(w, v.w, acc[k].w);
        }
    }
}
// original layout: planes[bp][f][y][x], feature stride HP*HP
__device__ __forceinline__ void corner_d(const float* __restrict__ base,
                                         int x, int y, float w, float4 acc[8]) {
    if ((unsigned)x < HP && (unsigned)y < HP) {
        const float* p = base + ((size_t)y * HP + x);
        #pragma unroll
        for (int k = 0; k < 8; ++k) {
            float* a = &acc[k].x;
            #pragma unroll
            for (int c = 0; c < 4; ++c) {
                float v = p[(size_t)(k * 4 + c) * (HP * HP)];
                a[c] = fmaf(w, v, a[c]);
            }
        }
    }
}

template<bool TRANS>
__device__ __forceinline__ void sample_plane(const float* __restrict__ base,
                                             float gx, float gy, float4 acc[8]) {
    float px = (gx + 1.0f) * 0.5f * (float)(HP - 1);
    float py = (gy + 1.0f) * 0.5f * (float)(HP - 1);
    float fx = floorf(px), fy = floorf(py);
    float wx = px - fx,    wy = py - fy;
    int x0 = (int)fx, y0 = (int)fy;
    int x1 = x0 + 1,  y1 = y0 + 1;
    float w00 = (1.0f - wx) * (1.0f - wy);
    float w10 = wx * (1.0f - wy);
    float w01 = (1.0f - wx) * wy;
    float w11 = wx * wy;
    if (TRANS) {
        corner_t(base, x0, y0, w00, acc);
        corner_t(base, x1, y0, w10, acc);
        corner_t(base, x0, y1, w01, acc);
        corner_t(base, x1, y1, w11, acc);
    } else {
        corner_d(base, x0, y0, w00, acc);
        corner_d(base, x1, y0, w10, acc);
        corner_d(base, x0, y1, w01, acc);
        corner_d(base, x1, y1, w11, acc);
    }
}

// ---- transpose planes [B*3,F,H,W] -> [B*3,H,W,F] -----------------------
__global__ __launch_bounds__(256)
void transpose_planes(const float* __restrict__ planes, float* __restrict__ pT) {
    int idx = blockIdx.x * 256 + threadIdx.x;       // over B*3*HP*HP
    int xy = idx % (HP * HP);
    int bp = idx / (HP * HP);
    const float* src = planes + (size_t)bp * FEAT * HP * HP + xy;
    float4 v[8];
    #pragma unroll
    for (int k = 0; k < 8; ++k) {
        v[k].x = src[(size_t)(4 * k + 0) * HP * HP];
        v[k].y = src[(size_t)(4 * k + 1) * HP * HP];
        v[k].z = src[(size_t)(4 * k + 2) * HP * HP];
        v[k].w = src[(size_t)(4 * k + 3) * HP * HP];
    }
    float4* dst = (float4*)(pT + (size_t)idx * FEAT);
    #pragma unroll
    for (int k = 0; k < 8; ++k) dst[k] = v[k];
}

// ---- fused sample + MLP + composite ------------------------------------
// block = 192 threads = 4 rays x 48 samples
template<bool TRANS>
__global__ __launch_bounds__(192)
void render_kernel(const float* __restrict__ pl,
                   const float* __restrict__ rayo,
                   const float* __restrict__ rayd,
                   const float* __restrict__ jitter,
                   const float* __restrict__ W1, const float* __restrict__ b1,
                   const float* __restrict__ W2, const float* __restrict__ b2,
                   float* __restrict__ out) {
    __shared__ float4 smp[192];
    __shared__ float  sds[192];

    int tid = threadIdx.x;
    int lr  = tid / NS;          // local ray 0..3
    int n   = tid - lr * NS;     // sample idx 0..47
    int ray = blockIdx.x * 4 + lr;
    int b   = ray >> 12;         // ray / RAYS

    float jit = jitter[ray * NS + n];
    float sd  = (float)n * S_DELTA + jit * S_DELTA;   // sdist == tdist here

    float ox = rayo[ray * 3 + 0], oy = rayo[ray * 3 + 1], oz = rayo[ray * 3 + 2];
    float dx = rayd[ray * 3 + 0], dy = rayd[ray * 3 + 1], dz = rayd[ray * 3 + 2];
    float cx = fmaf(sd, dx, ox);
    float cy = fmaf(sd, dy, oy);
    float cz = fmaf(sd, dz, oz);

    float4 acc[8];
    #pragma unroll
    for (int k = 0; k < 8; ++k) acc[k] = make_float4(0.f, 0.f, 0.f, 0.f);

    const size_t psz = (size_t)HP * HP * FEAT;
    const float* base = pl + (size_t)b * 3 * psz;
    sample_plane<TRANS>(base,           cx, cy, acc);   // plane (x,y)
    sample_plane<TRANS>(base + psz,     cx, cz, acc);   // plane (x,z)
    sample_plane<TRANS>(base + 2 * psz, cy, cz, acc);   // plane (y,z)

    // mean over 3 planes
    float xv[32];
    #pragma unroll
    for (int k = 0; k < 8; ++k) {
        xv[4 * k + 0] = acc[k].x * (1.0f / 3.0f);
        xv[4 * k + 1] = acc[k].y * (1.0f / 3.0f);
        xv[4 * k + 2] = acc[k].z * (1.0f / 3.0f);
        xv[4 * k + 3] = acc[k].w * (1.0f / 3.0f);
    }

    // MLP: h = softplus(x@W1 + b1); o = h@W2 + b2
    // W1 rows are contiguous & wave-uniform -> scalar loads
    float h[HID];
    #pragma unroll
    for (int j = 0; j < HID; ++j) h[j] = b1[j];
    #pragma unroll
    for (int f = 0; f < FEAT; ++f) {
        float xf = xv[f];
        #pragma unroll
        for (int j = 0; j < HID; ++j)
            h[j] = fmaf(xf, W1[f * HID + j], h[j]);
    }
    float o0 = b2[0], o1 = b2[1], o2 = b2[2], o3 = b2[3];
    #pragma unroll
    for (int j = 0; j < HID; ++j) {
        float hh = softplus_f(h[j]);
        o0 = fmaf(hh, W2[j * 4 + 0], o0);
        o1 = fmaf(hh, W2[j * 4 + 1], o1);
        o2 = fmaf(hh, W2[j * 4 + 2], o2);
        o3 = fmaf(hh, W2[j * 4 + 3], o3);
    }

    smp[tid] = make_float4(softplus_f(o0),
                           sigmoid_f(o1) * 1.002f - 0.001f,
                           sigmoid_f(o2) * 1.002f - 0.001f,
                           sigmoid_f(o3) * 1.002f - 0.001f);
    sds[tid] = sd;
    __syncthreads();

    if (tid < 4) {
        int rray = blockIdx.x * 4 + tid;
        const float4* sp  = &smp[tid * NS];
        const float*  sdp = &sds[tid * NS];
        float T = 1.0f, rf = 0.f, gf = 0.f, bf = 0.f, dep = 0.f, wsum = 0.f;
        for (int m = 0; m < NS; ++m) {
            float4 v  = sp[m];
            float sdc = sdp[m];
            float delta = (m < NS - 1) ? (sdp[m + 1] - sdc) : 1e10f;
            float alpha = 1.0f - __expf(-delta * v.x);
            float w = alpha * T;
            rf = fmaf(w, v.y, rf);
            gf = fmaf(w, v.z, gf);
            bf = fmaf(w, v.w, bf);
            dep = fmaf(w, sdc, dep);
            wsum += w;
            T *= (1.0f - alpha + 1e-10f);
        }
        out[rray * 3 + 0] = rf;
        out[rray * 3 + 1] = gf;
        out[rray * 3 + 2] = bf;
        out[NRAY * 3 + rray] = dep;   // depth
        out[NRAY * 4 + rray] = wsum;  // weights sum
        out[NRAY * 5 + rray] = T;     // final transmittance
    }
}

extern "C" void kernel_launch(void* const* d_in, const int* in_sizes, int n_in,
                              void* d_out, int out_size, void* d_ws, size_t ws_size,
                              hipStream_t stream) {
    const float* planes = (const float*)d_in[0];
    const float* rayo   = (const float*)d_in[1];
    const float* rayd   = (const float*)d_in[2];
    const float* jitter = (const float*)d_in[3];
    const float* W1     = (const float*)d_in[4];
    const float* b1     = (const float*)d_in[5];
    const float* W2     = (const float*)d_in[6];
    const float* b2     = (const float*)d_in[7];
    float* out = (float*)d_out;

    const size_t ptBytes = (size_t)BATCH * 3 * HP * HP * FEAT * sizeof(float);
    dim3 rblk(192), rgrd(NRAY / 4);

    if (ws_size >= ptBytes) {
        float* pT = (float*)d_ws;
        hipLaunchKernelGGL(transpose_planes, dim3(BATCH * 3 * HP * HP / 256), dim3(256),
                           0, stream, planes, pT);
        hipLaunchKernelGGL((render_kernel<true>), rgrd, rblk, 0, stream,
                           pT, rayo, rayd, jitter, W1, b1, W2, b2, out);
    } else {
        hipLaunchKernelGGL((render_kernel<false>), rgrd, rblk, 0, stream,
                           planes, rayo, rayd, jitter, W1, b1, W2, b2, out);
    }
}